// Round 4
// baseline (185.959 us; speedup 1.0000x reference)
//
#include <hip/hip_runtime.h>
#include <hip/hip_bf16.h>

#define B_   64
#define NW_  256
#define H_   768

#define AB_    (0.1f / 768.0f)   // ALPHA*BETA
#define OMB_   0.9f              // 1 - BETA
#define K1_    0.1f
#define BP_    1.2f
#define AVDL_  50.0f

typedef __bf16 bf16x8 __attribute__((ext_vector_type(8)));
typedef float  f32x4  __attribute__((ext_vector_type(4)));

// ---------------------------------------------------------------------------
// Fragment-direct GEMM, fused score epilogue. R3 post-mortem: four
// structurally different LDS-staged versions (occupancy 9%->36%, barrier
// domains 2->4, depth 2/3) all ~44-49us, no pipe >35%. The shared structure
// was the suspect: global->VGPR->cvt->LDS->barrier->ds_read->MFMA, with the
// LDS round-trip + barrier-serialized iteration on the critical path 24x.
// Staging only amortized each byte across TWO waves - not worth the
// machinery (learn_hip common-mistake #7). R4 deletes it entirely:
//   - MFMA fragments load DIRECTLY from global. A-frag wave-load (row=
//     lane&15, k-seg=(lane>>4)*8) covers 16 x 128B lines FULLY (4 lanes
//     consume each row's 32-float k-chunk line) - perfect coalescing.
//   - f32->bf16 cvt moves to the consumer (compiler emits v_cvt_pk).
//   - NO barriers in the K-loop; compiler hoists loads freely under
//     fine-grained vmcnt. No bank conflicts, no ds ops, no staging VALU.
// Tile 128x64 per block, 4 waves; wave w owns rows w*32..w*32+31 (A-frags
// unique per wave; per-chunk B tile is 8KB -> 4x wave redundancy served by
// L1). Grid 512 = 8 tiles x 64 batches, bid=t*64+b -> XCD b%8: one batch's
// tiles share an XCD-L2. K fully unrolled: all offsets are literals
// (kc*128B <= 2944 < 4096 imm limit).
// ---------------------------------------------------------------------------
__global__ __launch_bounds__(256, 2) void gemm_fused(
    const float* __restrict__ q_rep, const float* __restrict__ d_rep,
    const int* __restrict__ q_ids, const int* __restrict__ d_ids,
    const int* __restrict__ d_tfs,
    float* __restrict__ S, float* __restrict__ ws_etdf)
{
    __shared__ float mq_s[128];     // q null mask
    __shared__ float md_s[64];      // d null mask
    __shared__ float mdtf_s[64];    // md * tf
    __shared__ float tf_s[64];      // raw tf (em term is unmasked)
    __shared__ int4  qk_s[128];     // q id keys
    __shared__ int4  dk_s[64];      // d id keys

    const int tid  = threadIdx.x;
    const int wave = tid >> 6;
    const int lane = tid & 63;
    const int bid  = blockIdx.x;
    const int b    = bid & 63;
    const int t    = bid >> 6;          // tile 0..7
    const int m0   = (t & 1) * 128;     // 2 m-tiles of 128
    const int n0   = (t >> 1) * 64;     // 4 n-tiles of 64

    // Masks / keys / tf into LDS (one barrier total, before the K-loop).
    if (tid < 128) {
        int4 qa = *(const int4*)(q_ids + ((size_t)b * NW_ + m0 + tid) * 4);
        qk_s[tid] = qa;
        mq_s[tid] = (qa.x == 0 && qa.y == 0 && qa.z == 0 && qa.w == 0) ? 0.f : 1.f;
    } else if (tid < 192) {
        const int r = tid - 128;
        int4 da = *(const int4*)(d_ids + ((size_t)b * NW_ + n0 + r) * 4);
        dk_s[r] = da;
        float md = (da.x == 0 && da.y == 0 && da.z == 0 && da.w == 0) ? 0.f : 1.f;
        float tf = (float)d_tfs[(size_t)b * NW_ + n0 + r];
        md_s[r]   = md;
        tf_s[r]   = tf;
        mdtf_s[r] = md * tf;
    }
    __syncthreads();

    // Fragment-direct base pointers. MFMA 16x16x32 A/B frag: lane reads
    // 8 consecutive k-elements of row fr=lane&15 starting at fk=(lane>>4)*8.
    const int fr = lane & 15;
    const int fk = (lane >> 4) * 8;

    // A rows: m0 + wave*32 + i*16 + fr (i=0,1). B rows: n0 + j*16 + fr.
    const float* A_0 = q_rep + ((size_t)b * NW_ + m0 + wave * 32 + fr) * H_ + fk;
    const float* A_1 = A_0 + 16 * H_;
    const float* B_0 = d_rep + ((size_t)b * NW_ + n0 + fr) * H_ + fk;
    const float* B_1 = B_0 + 16 * H_;
    const float* B_2 = B_0 + 32 * H_;
    const float* B_3 = B_0 + 48 * H_;

    f32x4 acc[2][4];
#pragma unroll
    for (int i = 0; i < 2; ++i)
#pragma unroll
        for (int j = 0; j < 4; ++j)
            acc[i][j] = (f32x4){0.f, 0.f, 0.f, 0.f};

#pragma unroll
    for (int kc = 0; kc < 24; ++kc) {
        // 12 dwordx4 loads, all at literal offsets kc*128(+16) bytes.
        float4 a0l = *(const float4*)(A_0 + kc * 32);
        float4 a0h = *(const float4*)(A_0 + kc * 32 + 4);
        float4 a1l = *(const float4*)(A_1 + kc * 32);
        float4 a1h = *(const float4*)(A_1 + kc * 32 + 4);
        float4 b0l = *(const float4*)(B_0 + kc * 32);
        float4 b0h = *(const float4*)(B_0 + kc * 32 + 4);
        float4 b1l = *(const float4*)(B_1 + kc * 32);
        float4 b1h = *(const float4*)(B_1 + kc * 32 + 4);
        float4 b2l = *(const float4*)(B_2 + kc * 32);
        float4 b2h = *(const float4*)(B_2 + kc * 32 + 4);
        float4 b3l = *(const float4*)(B_3 + kc * 32);
        float4 b3h = *(const float4*)(B_3 + kc * 32 + 4);

        auto mk = [](const float4& lo, const float4& hi) -> bf16x8 {
            return (bf16x8){ (__bf16)lo.x, (__bf16)lo.y, (__bf16)lo.z, (__bf16)lo.w,
                             (__bf16)hi.x, (__bf16)hi.y, (__bf16)hi.z, (__bf16)hi.w };
        };
        bf16x8 af[2] = { mk(a0l, a0h), mk(a1l, a1h) };
        bf16x8 bf[4] = { mk(b0l, b0h), mk(b1l, b1h), mk(b2l, b2h), mk(b3l, b3h) };

#pragma unroll
        for (int i = 0; i < 2; ++i)
#pragma unroll
            for (int j = 0; j < 4; ++j)
                acc[i][j] = __builtin_amdgcn_mfma_f32_16x16x32_bf16(
                    af[i], bf[j], acc[i][j], 0, 0, 0);
    }

    // Epilogue. C layout: col = lane&15, row = (lane>>4)*4 + reg.
    // etdf contribution per (row, col): AB*mq*md*v*tf + 0.9*em*tf.
    const int cn = lane & 15;
    const int qg = lane >> 4;
    float md_l[4], mdtf_l[4], tf_l[4];
    int4  dk_l[4];
#pragma unroll
    for (int j = 0; j < 4; ++j) {
        const int c = j * 16 + cn;
        md_l[j]   = md_s[c];
        mdtf_l[j] = mdtf_s[c];
        tf_l[j]   = tf_s[c];
        dk_l[j]   = dk_s[c];
    }
    float* Sbase = S + ((size_t)b * NW_ + m0 + wave * 32) * NW_ + n0;

    float rs[8];
#pragma unroll
    for (int i = 0; i < 2; ++i)
#pragma unroll
        for (int r = 0; r < 4; ++r) {
            const int row = i * 16 + qg * 4 + r;
            const float mq = mq_s[wave * 32 + row];
            const int4  qk = qk_s[wave * 32 + row];
            float sdot = 0.f, sem = 0.f;
#pragma unroll
            for (int j = 0; j < 4; ++j) {
                const float v = acc[i][j][r];
                Sbase[(size_t)row * NW_ + j * 16 + cn] = v * mq * md_l[j];
                sdot += v * mdtf_l[j];
                const int4 dk = dk_l[j];
                if (dk.x == qk.x && dk.y == qk.y && dk.z == qk.z && dk.w == qk.w)
                    sem += tf_l[j];
            }
            rs[i * 4 + r] = mq * AB_ * sdot + OMB_ * sem;
        }
    // Reduce over the 16 lanes of each quad-group (rows identical there).
#pragma unroll
    for (int off = 1; off <= 8; off <<= 1)
#pragma unroll
        for (int e = 0; e < 8; ++e)
            rs[e] += __shfl_xor(rs[e], off);
    if (cn == 0) {
#pragma unroll
        for (int i = 0; i < 2; ++i)
#pragma unroll
            for (int r = 0; r < 4; ++r)
                atomicAdd(&ws_etdf[(size_t)b * NW_ + m0 + wave * 32 + i * 16 + qg * 4 + r],
                          rs[i * 4 + r]);
    }
}

// ---------------------------------------------------------------------------
// Final: per batch, dl = sum(tf); dtw = 1.1*etdf/(etdf + K1*(1-Bp+Bp*dl/AVDL)
// + 1e-8); s[b] = sum_q qtw*dtw.  One wave per batch.
// ---------------------------------------------------------------------------
__global__ __launch_bounds__(64) void final_kernel(
    const float* __restrict__ ws_etdf, const int* __restrict__ d_tfs,
    const float* __restrict__ qtw, float* __restrict__ out)
{
    const int b = blockIdx.x;
    const int lane = threadIdx.x;

    float4 ev = *(const float4*)(ws_etdf + (size_t)b * NW_ + lane * 4);
    int4  tf4 = *(const int4*)(d_tfs   + (size_t)b * NW_ + lane * 4);
    float4 qv = *(const float4*)(qtw    + (size_t)b * NW_ + lane * 4);

    float dl = (float)(tf4.x + tf4.y + tf4.z + tf4.w);
#pragma unroll
    for (int off = 32; off; off >>= 1) dl += __shfl_xor(dl, off);

    const float c = K1_ * (1.f - BP_ + BP_ * dl / AVDL_);
    float ew[4] = {ev.x, ev.y, ev.z, ev.w};
    float qw[4] = {qv.x, qv.y, qv.z, qv.w};
    float s = 0.f;
#pragma unroll
    for (int j = 0; j < 4; ++j)
        s += qw[j] * (ew[j] * (1.f + K1_)) / (ew[j] + c + 1e-8f);
#pragma unroll
    for (int off = 32; off; off >>= 1) s += __shfl_xor(s, off);
    if (lane == 0) out[b] = s;
}

extern "C" void kernel_launch(void* const* d_in, const int* in_sizes, int n_in,
                              void* d_out, int out_size, void* d_ws, size_t ws_size,
                              hipStream_t stream)
{
    const float* q_rep = (const float*)d_in[0];
    const float* d_rep = (const float*)d_in[1];
    const float* qtw   = (const float*)d_in[2];
    const int*   q_ids = (const int*)d_in[3];
    const int*   d_ids = (const int*)d_in[4];
    const int*   d_tfs = (const int*)d_in[5];

    float* out = (float*)d_out;
    float* S   = out + B_;              // d_expanded_tf, [B, NW, NW]
    float* ws_etdf = (float*)d_ws;      // [B, NW] f32

    hipMemsetAsync(ws_etdf, 0, (size_t)B_ * NW_ * sizeof(float), stream);

    gemm_fused<<<512, 256, 0, stream>>>(q_rep, d_rep, q_ids, d_ids, d_tfs,
                                        S, ws_etdf);
    final_kernel<<<B_, 64, 0, stream>>>(ws_etdf, d_tfs, qtw, out);
}

// Round 5
// 152.847 us; speedup vs baseline: 1.2166x; 1.2166x over previous
//
#include <hip/hip_runtime.h>
#include <hip/hip_bf16.h>

#define B_   64
#define NW_  256
#define H_   768

#define AB_    (0.1f / 768.0f)   // ALPHA*BETA
#define OMB_   0.9f              // 1 - BETA
#define K1_    0.1f
#define BP_    1.2f
#define AVDL_  50.0f

typedef __bf16 bf16x4 __attribute__((ext_vector_type(4)));
typedef __bf16 bf16x8 __attribute__((ext_vector_type(8)));
typedef float  f32x4  __attribute__((ext_vector_type(4)));

// ---------------------------------------------------------------------------
// 64x64-tile GEMM, BK=256, 3 K-iterations, fused score epilogue.
// R0-R4 post-mortem: every 24-chunk barrier-cadence variant sat at 44-49us
// with NO pipe >35%. Per-chunk pipe arithmetic (TA ~800cyc on 8-segment
// scattered loads, LDS ~900, VALU ~200, MFMA ~300) sums to the observed
// ~2000cyc/chunk: pipes are moderately loaded and NON-overlapping - the
// barrier cadence convoys all resident waves into the same phase 24 times.
// R4 (fragment-direct) showed the failure mode of dropping LDS: scattered
// 16-row fragment loads thrash L1 -> 83us. R5 keeps LDS but restructures:
//   - BK=256: 3 iterations, 7 barriers total (vs 48). Long homogeneous
//     phases run each pipe at full rate even when waves convoy.
//   - Whole-row staging loads: one wave-load = one row's 1KB K-slice,
//     fully contiguous (TA-optimal; vs 8 scattered 128B segments).
//   - Full next-slice register lookahead (32 float4/wave, ~128 VGPR),
//     issued at top of compute phase; 600+cyc of ds_read+MFMA covers
//     global latency. __launch_bounds__(256,2) caps VGPR at 256 (R1's
//     collapse came from the 128 cap - do NOT request 4 waves/EU).
//   - Combined LDS tile Cs[128][264] (A rows 0-63, B rows 64-127), +8
//     bf16 pad: b128 frag reads are <=2-way bank aliased (free, m136);
//     b64 staged writes 2-way (free). 69KB -> 2 blocks/CU anti-phased:
//     one block's compute covers the other's staging.
// Grid 1024 = 16 tiles x 64 batches, bid=t*64+b -> XCD=b%8: one batch's
// tiles share an XCD L2. Wave w: quadrant qm=w>>1, qn=w&1 (32x32 out).
// ---------------------------------------------------------------------------
__global__ __launch_bounds__(256, 2) void gemm_fused(
    const float* __restrict__ q_rep, const float* __restrict__ d_rep,
    const int* __restrict__ q_ids, const int* __restrict__ d_ids,
    const int* __restrict__ d_tfs,
    float* __restrict__ S, float* __restrict__ ws_etdf)
{
    // A|B combined: rows 0-63 = A(m0..m0+63), rows 64-127 = B(n0..n0+63).
    // 264 = 256 + 8 pad (16B-aligned rows, stride 528B = 132 dwords).
    __shared__ __align__(16) __bf16 Cs[128][264];   // 67.6 KB
    __shared__ float mq_s[64];      // q null mask
    __shared__ float md_s[64];      // d null mask
    __shared__ float mdtf_s[64];    // md * tf
    __shared__ float tf_s[64];      // raw tf (em term is unmasked)
    __shared__ int4  qk_s[64];      // q id keys
    __shared__ int4  dk_s[64];      // d id keys

    const int tid  = threadIdx.x;
    const int wave = tid >> 6;
    const int lane = tid & 63;
    const int bid  = blockIdx.x;
    const int b    = bid & 63;
    const int t    = bid >> 6;          // tile 0..15
    const int m0   = (t & 3) * 64;      // 4 m-tiles of 64
    const int n0   = (t >> 2) * 64;     // 4 n-tiles of 64

    // Masks / keys / tf into LDS (covered by the first __syncthreads).
    if (tid < 64) {
        int4 qa = *(const int4*)(q_ids + ((size_t)b * NW_ + m0 + tid) * 4);
        qk_s[tid] = qa;
        mq_s[tid] = (qa.x == 0 && qa.y == 0 && qa.z == 0 && qa.w == 0) ? 0.f : 1.f;
    } else if (tid < 128) {
        const int r = tid - 64;
        int4 da = *(const int4*)(d_ids + ((size_t)b * NW_ + n0 + r) * 4);
        dk_s[r] = da;
        float md = (da.x == 0 && da.y == 0 && da.z == 0 && da.w == 0) ? 0.f : 1.f;
        float tf = (float)d_tfs[(size_t)b * NW_ + n0 + r];
        md_s[r]   = md;
        tf_s[r]   = tf;
        mdtf_s[r] = md * tf;
    }

    // Staging: wave w owns combined rows [w*32, w*32+32). Waves 0-1 stage A,
    // waves 2-3 stage B. One wave-load = one row's 1KB slice (lane*16B).
    const float* gbase = (wave < 2)
        ? q_rep + ((size_t)b * NW_ + m0 + wave * 32) * H_
        : d_rep + ((size_t)b * NW_ + n0 + (wave - 2) * 32) * H_;
    const float* gl = gbase + lane * 4;             // + i*H_ + ko*256
    __bf16* lbase = &Cs[wave * 32][0] + lane * 4;   // + i*264

    // Full next-slice lookahead: 32 float4 = 128 VGPR, literal-indexed only.
    float4 rr[32];
    auto ldall = [&](int ko) {
#pragma unroll
        for (int i = 0; i < 32; ++i)
            rr[i] = *(const float4*)(gl + (size_t)i * H_ + ko * 256);
    };
    auto stall = [&]() {
#pragma unroll
        for (int i = 0; i < 32; ++i) {
            bf16x4 v = { (__bf16)rr[i].x, (__bf16)rr[i].y,
                         (__bf16)rr[i].z, (__bf16)rr[i].w };
            *(bf16x4*)(lbase + i * 264) = v;
        }
    };

    f32x4 acc[2][2];
#pragma unroll
    for (int i = 0; i < 2; ++i)
#pragma unroll
        for (int j = 0; j < 2; ++j)
            acc[i][j] = (f32x4){0.f, 0.f, 0.f, 0.f};

    const int fr = lane & 15;
    const int fk = (lane >> 4) * 8;
    const int qm = wave >> 1;           // quadrant row (32-row strip)
    const int qn = wave & 1;            // quadrant col (32-col strip)

    // Prologue: stage K-slice 0.
    ldall(0);
    stall();
    __syncthreads();

#pragma unroll
    for (int ko = 0; ko < 3; ++ko) {
        // Issue next slice's global loads first; ds_read+MFMA below (~600+
        // cyc) covers their latency; the barrier's vmcnt drain lands after.
        if (ko < 2) ldall(ko + 1);
#pragma unroll
        for (int ks = 0; ks < 8; ++ks) {
            bf16x8 af[2], bfr[2];
#pragma unroll
            for (int t2 = 0; t2 < 2; ++t2) {
                af[t2]  = *(bf16x8*)&Cs[qm * 32 + t2 * 16 + fr][ks * 32 + fk];
                bfr[t2] = *(bf16x8*)&Cs[64 + qn * 32 + t2 * 16 + fr][ks * 32 + fk];
            }
#pragma unroll
            for (int i = 0; i < 2; ++i)
#pragma unroll
                for (int j = 0; j < 2; ++j)
                    acc[i][j] = __builtin_amdgcn_mfma_f32_16x16x32_bf16(
                        af[i], bfr[j], acc[i][j], 0, 0, 0);
        }
        __syncthreads();                // compute done; LDS reusable
        if (ko < 2) {
            stall();                    // write slice ko+1
            __syncthreads();            // slice visible to all waves
        }
    }

    // Epilogue. C layout: col = lane&15, row = (lane>>4)*4 + reg.
    // etdf contribution per (row, col): AB*mq*md*v*tf + 0.9*em*tf.
    const int cn = lane & 15;
    const int qg = lane >> 4;
    float md_l[2], mdtf_l[2], tf_l[2];
    int4  dk_l[2];
#pragma unroll
    for (int j = 0; j < 2; ++j) {
        const int c = qn * 32 + j * 16 + cn;
        md_l[j]   = md_s[c];
        mdtf_l[j] = mdtf_s[c];
        tf_l[j]   = tf_s[c];
        dk_l[j]   = dk_s[c];
    }
    float* Sbase = S + ((size_t)b * NW_ + m0 + qm * 32) * NW_ + n0 + qn * 32;

    float rs[8];
#pragma unroll
    for (int i = 0; i < 2; ++i)
#pragma unroll
        for (int r = 0; r < 4; ++r) {
            const int row = i * 16 + qg * 4 + r;
            const float mq = mq_s[qm * 32 + row];
            const int4  qk = qk_s[qm * 32 + row];
            float sdot = 0.f, sem = 0.f;
#pragma unroll
            for (int j = 0; j < 2; ++j) {
                const float v = acc[i][j][r];
                Sbase[(size_t)row * NW_ + j * 16 + cn] = v * mq * md_l[j];
                sdot += v * mdtf_l[j];
                const int4 dk = dk_l[j];
                if (dk.x == qk.x && dk.y == qk.y && dk.z == qk.z && dk.w == qk.w)
                    sem += tf_l[j];
            }
            rs[i * 4 + r] = mq * AB_ * sdot + OMB_ * sem;
        }
    // Reduce over the 16 lanes of each quad-group (rows identical there).
#pragma unroll
    for (int off = 1; off <= 8; off <<= 1)
#pragma unroll
        for (int e = 0; e < 8; ++e)
            rs[e] += __shfl_xor(rs[e], off);
    if (cn == 0) {
#pragma unroll
        for (int i = 0; i < 2; ++i)
#pragma unroll
            for (int r = 0; r < 4; ++r)
                atomicAdd(&ws_etdf[(size_t)b * NW_ + m0 + qm * 32 + i * 16 + qg * 4 + r],
                          rs[i * 4 + r]);
    }
}

// ---------------------------------------------------------------------------
// Final: per batch, dl = sum(tf); dtw = 1.1*etdf/(etdf + K1*(1-Bp+Bp*dl/AVDL)
// + 1e-8); s[b] = sum_q qtw*dtw.  One wave per batch.
// ---------------------------------------------------------------------------
__global__ __launch_bounds__(64) void final_kernel(
    const float* __restrict__ ws_etdf, const int* __restrict__ d_tfs,
    const float* __restrict__ qtw, float* __restrict__ out)
{
    const int b = blockIdx.x;
    const int lane = threadIdx.x;

    float4 ev = *(const float4*)(ws_etdf + (size_t)b * NW_ + lane * 4);
    int4  tf4 = *(const int4*)(d_tfs   + (size_t)b * NW_ + lane * 4);
    float4 qv = *(const float4*)(qtw    + (size_t)b * NW_ + lane * 4);

    float dl = (float)(tf4.x + tf4.y + tf4.z + tf4.w);
#pragma unroll
    for (int off = 32; off; off >>= 1) dl += __shfl_xor(dl, off);

    const float c = K1_ * (1.f - BP_ + BP_ * dl / AVDL_);
    float ew[4] = {ev.x, ev.y, ev.z, ev.w};
    float qw[4] = {qv.x, qv.y, qv.z, qv.w};
    float s = 0.f;
#pragma unroll
    for (int j = 0; j < 4; ++j)
        s += qw[j] * (ew[j] * (1.f + K1_)) / (ew[j] + c + 1e-8f);
#pragma unroll
    for (int off = 32; off; off >>= 1) s += __shfl_xor(s, off);
    if (lane == 0) out[b] = s;
}

extern "C" void kernel_launch(void* const* d_in, const int* in_sizes, int n_in,
                              void* d_out, int out_size, void* d_ws, size_t ws_size,
                              hipStream_t stream)
{
    const float* q_rep = (const float*)d_in[0];
    const float* d_rep = (const float*)d_in[1];
    const float* qtw   = (const float*)d_in[2];
    const int*   q_ids = (const int*)d_in[3];
    const int*   d_ids = (const int*)d_in[4];
    const int*   d_tfs = (const int*)d_in[5];

    float* out = (float*)d_out;
    float* S   = out + B_;              // d_expanded_tf, [B, NW, NW]
    float* ws_etdf = (float*)d_ws;      // [B, NW] f32

    hipMemsetAsync(ws_etdf, 0, (size_t)B_ * NW_ * sizeof(float), stream);

    gemm_fused<<<1024, 256, 0, stream>>>(q_rep, d_rep, q_ids, d_ids, d_tfs,
                                         S, ws_etdf);
    final_kernel<<<B_, 64, 0, stream>>>(ws_etdf, d_tfs, qtw, out);
}